// Round 1
// baseline (803.243 us; speedup 1.0000x reference)
//
#include <hip/hip_runtime.h>

// CustomRNN: h_{t+1} = tanh([x_t | h_t] @ W_ih + b_ih), out = h_final @ W_ho + b_ho
// BATCH=512, SEQ=1024, IN=64, HID=256, CLS=10.
//
// Design: 32 blocks x 512 threads (8 waves). Each block owns 16 batch rows for
// all 1024 steps (recurrence is per-row independent -> no inter-block sync).
// W_ih (320x256) lives in REGISTERS as bf16 MFMA B-fragments, distributed
// across the 8 waves (each wave owns a 32-column slice: 20 frags = 80 VGPRs).
// The A-panel [x_t | h_t] (16x320 bf16, 10 KB) lives in LDS, double-buffered,
// XOR-swizzled (row stride 640 B would otherwise be a 16-way bank conflict on
// ds_read_b128). x_{t+1} is prefetched from HBM inside each step.

#define BATCH 512
#define SEQ   1024
#define INP   64
#define HID   256
#define CLS   10
#define KTOT  (INP + HID)        // 320
#define ROWS  16                 // batch rows per block
#define NWAVES 8
#define NTHREADS (NWAVES * 64)   // 512
#define ROWB  (KTOT * 2)         // 640 bytes per A-panel row
#define NK    (KTOT / 32)        // 10 k-tiles of 32

typedef short bf16x8 __attribute__((ext_vector_type(8)));
typedef float f32x4  __attribute__((ext_vector_type(4)));

static __device__ __forceinline__ unsigned short f2bf(float f) {
  union { float f; unsigned int u; } v; v.f = f;
  unsigned int u = v.u;
  u += 0x7FFFu + ((u >> 16) & 1u);   // round-to-nearest-even
  return (unsigned short)(u >> 16);
}
static __device__ __forceinline__ float bf2f(unsigned short b) {
  union { unsigned int u; float f; } v; v.u = ((unsigned int)b) << 16;
  return v.f;
}
static __device__ __forceinline__ float fast_exp2(float x) {
#if __has_builtin(__builtin_amdgcn_exp2f)
  return __builtin_amdgcn_exp2f(x);
#else
  return __exp2f(x);
#endif
}
static __device__ __forceinline__ float fast_rcp(float x) {
#if __has_builtin(__builtin_amdgcn_rcpf)
  return __builtin_amdgcn_rcpf(x);
#else
  return 1.0f / x;
#endif
}
// tanh(x) = 1 - 2/(exp(2x)+1); exp(2x) = exp2(2*log2(e)*x). Branch-free,
// saturates correctly for |x| large (exp2 -> inf/0).
static __device__ __forceinline__ float fast_tanh(float x) {
  float e = fast_exp2(x * 2.8853900817779268f);
  return 1.0f - 2.0f * fast_rcp(1.0f + e);
}

// XOR swizzle: byte-in-row ^ ((row&7)<<4). Row stride 640 = 5*128, so each row
// is whole 128B windows; XOR of bits 4..6 stays in-row and spreads the 16
// same-column lanes of a ds_read_b128 across 8 distinct 16B slots (2-way = free).
static __device__ __forceinline__ int swz(int row, int byteInRow) {
  return row * ROWB + (byteInRow ^ ((row & 7) << 4));
}

__global__ __launch_bounds__(NTHREADS, 2)
void rnn_scan_kernel(const float* __restrict__ x,
                     const float* __restrict__ W_ih,
                     const float* __restrict__ b_ih,
                     const float* __restrict__ W_ho,
                     const float* __restrict__ b_ho,
                     float* __restrict__ out) {
  __shared__ __align__(128) unsigned char sA[2][ROWS * ROWB];  // 2 x 10240 B

  const int tid  = threadIdx.x;
  const int lane = tid & 63;
  const int wave = tid >> 6;
  const int b0   = blockIdx.x * ROWS;

  const int g    = (lane >> 4) & 3;   // k-group within fragment
  const int frow = lane & 15;         // A-row (for loads) / D-col (for stores)

  // ---- Preload W_ih as B-fragments (bf16) into registers; wave owns cols [32w,32w+32)
  const int n0 = wave * 32;
  bf16x8 bw[NK][2];
  float  bias[2];
#pragma unroll
  for (int nt = 0; nt < 2; ++nt) {
    const int col = n0 + nt * 16 + frow;
    bias[nt] = b_ih[col];
#pragma unroll
    for (int kt = 0; kt < NK; ++kt) {
      bf16x8 v;
#pragma unroll
      for (int i = 0; i < 8; ++i) {
        const int k = kt * 32 + g * 8 + i;   // B: col = lane&15, k = 8*(lane>>4)+i
        v[i] = (short)f2bf(W_ih[(size_t)k * HID + col]);
      }
      bw[kt][nt] = v;
    }
  }

  // ---- Prologue: zero h-region of buffer 0, stage x_0 into buffer 0
  for (int i = tid; i < ROWS * 128; i += NTHREADS) {       // h region: 128 dwords/row
    const int row = i >> 7, d = i & 127;
    *(unsigned int*)&sA[0][row * ROWB + 128 + d * 4] = 0u; // zeros are swizzle-invariant
  }
  {
    const int e = tid * 2, xrow = e >> 6, xc = e & 63;     // 2 floats per thread
    const float2 xv = *(const float2*)&x[((size_t)(b0 + xrow) * SEQ + 0) * INP + xc];
    const unsigned int packed =
        (unsigned int)f2bf(xv.x) | ((unsigned int)f2bf(xv.y) << 16);
    *(unsigned int*)&sA[0][swz(xrow, xc * 2)] = packed;
  }
  __syncthreads();

  // ---- Main scan loop: one barrier per step
  int cur = 0;
#pragma unroll 1
  for (int t = 0; t < SEQ; ++t) {
    // prefetch x_{t+1} (overlaps with MFMA below)
    const int tn = t + 1;
    const int e = tid * 2, xrow = e >> 6, xc = e & 63;
    float2 xv = make_float2(0.f, 0.f);
    if (tn < SEQ)
      xv = *(const float2*)&x[((size_t)(b0 + xrow) * SEQ + tn) * INP + xc];

    // A-panel fragments: lane reads row=frow, 8 bf16 at k = kt*32 + g*8
    bf16x8 a[NK];
#pragma unroll
    for (int kt = 0; kt < NK; ++kt)
      a[kt] = *(const bf16x8*)&sA[cur][swz(frow, kt * 64 + g * 16)];

    f32x4 acc0 = {0.f, 0.f, 0.f, 0.f};
    f32x4 acc1 = {0.f, 0.f, 0.f, 0.f};
#pragma unroll
    for (int kt = 0; kt < NK; ++kt) {
      acc0 = __builtin_amdgcn_mfma_f32_16x16x32_bf16(a[kt], bw[kt][0], acc0, 0, 0, 0);
      acc1 = __builtin_amdgcn_mfma_f32_16x16x32_bf16(a[kt], bw[kt][1], acc1, 0, 0, 0);
    }

    // epilogue: h_new = tanh(acc + bias) -> bf16 -> LDS buf[cur^1] h-region
    unsigned char* dst = sA[cur ^ 1];
    const int c0 = INP + n0 + frow;       // A-panel column of tile 0 output
    const int c1 = c0 + 16;               // tile 1
#pragma unroll
    for (int j = 0; j < 4; ++j) {
      const int row = g * 4 + j;          // D: col = lane&15, row = 4*(lane>>4)+j
      const float h0 = fast_tanh(acc0[j] + bias[0]);
      const float h1 = fast_tanh(acc1[j] + bias[1]);
      *(unsigned short*)&dst[swz(row, c0 * 2)] = f2bf(h0);
      *(unsigned short*)&dst[swz(row, c1 * 2)] = f2bf(h1);
    }
    // stage x_{t+1}
    if (tn < SEQ) {
      const unsigned int packed =
          (unsigned int)f2bf(xv.x) | ((unsigned int)f2bf(xv.y) << 16);
      *(unsigned int*)&dst[swz(xrow, xc * 2)] = packed;
    }
    __syncthreads();
    cur ^= 1;
  }

  // ---- Head: out = h_final @ W_ho + b_ho   (16 rows x 10 classes per block)
  if (tid < ROWS * CLS) {
    const int row = tid / CLS, cl = tid % CLS;
    float s = b_ho[cl];
#pragma unroll 8
    for (int k = 0; k < HID; ++k) {
      const unsigned short hb =
          *(const unsigned short*)&sA[cur][swz(row, (INP + k) * 2)];
      s += bf2f(hb) * W_ho[(size_t)k * CLS + cl];
    }
    out[(size_t)(b0 + row) * CLS + cl] = s;
  }
}

extern "C" void kernel_launch(void* const* d_in, const int* in_sizes, int n_in,
                              void* d_out, int out_size, void* d_ws, size_t ws_size,
                              hipStream_t stream) {
  const float* x    = (const float*)d_in[0];
  const float* W_ih = (const float*)d_in[1];
  const float* b_ih = (const float*)d_in[2];
  const float* W_ho = (const float*)d_in[3];
  const float* b_ho = (const float*)d_in[4];
  float* out = (float*)d_out;

  rnn_scan_kernel<<<BATCH / ROWS, NTHREADS, 0, stream>>>(x, W_ih, b_ih, W_ho, b_ho, out);
}